// Round 13
// baseline (120.571 us; speedup 1.0000x reference)
//
#include <hip/hip_runtime.h>
#include <cmath>

// FusionLoss = ms_ssim(fus,ir)+ms_ssim(fus,vi) + l1(max(map_ir,map_vi),fus)
//            + 10*mean(|max(|lap ir|,|lap vi|) - |lap fus||)
// Inputs: im_fus, im_ir, im_vi, map_ir, map_vi  each [32,1,512,512] fp32.
//
// d_ws layout (floats): [0..1024)    ssim partials  (1024 ssim blocks)
//                       [1024..3072) l1 partials    (2048 lapl1 blocks)
//                       [3072..5120) grad partials  (2048 lapl1 blocks)
//
// Journal: r2 atomics->partials. Spills: r5 (lb(64,4) cap 64), r8 (b128 srow
// quads), r10 (lb(256,4) cap 64). Empirical: VGPR cap = 256/N for
// launch_bounds(256,N). r9 pk-f32 pairs: ssim 72.9us @ VGPR 80. r11 fusion
// neutral-negative (HBM contention). r12 depth-2 prefetch NEUTRAL (73.4us) —
// load latency not the stall; occupancy pinned at 24% for EVERY 768-block
// grid => grid-starved (3 blocks/CU), HW allows 512/84=6 waves/SIMD.
// r13: geometry only — 32-row strips, grid (2,16,32)=1024 = 4 blocks/CU
// under lb(256,2) (VGPR 84 <= 128 cap, no r10 spill). +6% halo work for
// +33% waves/SIMD. GUARDS: VGPR==84ish (<=120), WRITE<=50KB else revert.

typedef float f32x2 __attribute__((ext_vector_type(2)));

struct GaussW { float w[11]; };

#define SSIM_C1 1.0e-4f
#define SSIM_C2 9.0e-4f

// One row step of the SSIM main loop. P is a literal 0..21 (compile-time
// after macro expansion): buffer parity, ring slots, finalize slot all fold.
#define SSIM_STEP(P, RF, RG, RV, RF2, RG2, RV2)                               \
    {                                                                         \
        const int r = rb + (P);                                               \
        if (r < in_rows) {   /* wave-uniform guard */                         \
            /* stage row r from prefetch buffer (ds_write_b64 + b32) */      \
            srow_fi[wv][lane] = (f32x2){RF, RG};                              \
            srow_v [wv][lane] = RV;                                           \
            if (extra) {                                                      \
                srow_fi[wv][64 + lane] = (f32x2){RF2, RG2};                   \
                srow_v [wv][64 + lane] = RV2;                                 \
            }                                                                 \
            __builtin_amdgcn_wave_barrier();  /* write->read order */         \
            /* depth-2 prefetch: row r+2 into the SAME buffer (freed by the  \
               ds_write above); consumed 2 rows later */                      \
            if (r + 2 < in_rows) {                                            \
                const size_t base = (size_t)(r0 + r + 2) * 512 + col;         \
                RF = Fp[base]; RG = Ip[base]; RV = Vp[base];                  \
                if (extra_ok) {                                               \
                    const size_t b2 = (size_t)(r0 + r + 2) * 512 + col2;      \
                    RF2 = Fp[b2]; RG2 = Ip[b2]; RV2 = Vp[b2];                 \
                }                                                             \
            }                                                                 \
            /* horizontal gaussian sums, packed-f32 where pairable */         \
            f32x2 hfhi  = (f32x2)(0.f);   /* {Sw*F,  Sw*I}  */                \
            f32x2 hffii = (f32x2)(0.f);   /* {Sw*F2, Sw*I2} */                \
            f32x2 hfifv = (f32x2)(0.f);   /* {Sw*FI, Sw*FV} */                \
            f32x2 hvvv  = (f32x2)(0.f);   /* {Sw*V,  Sw*V2} */                \
            _Pragma("unroll")                                                 \
            for (int k = 0; k < 11; ++k) {                                    \
                const float t = w6[k < 6 ? k : 10 - k];                       \
                const f32x2 fi = srow_fi[wv][lane + k];                       \
                const float V  = srow_v [wv][lane + k];                       \
                const f32x2 t2 = (f32x2){t, t};                               \
                const f32x2 tfi = t2 * fi;                                    \
                hfhi  = __builtin_elementwise_fma(t2,  fi, hfhi);             \
                hffii = __builtin_elementwise_fma(tfi, fi, hffii);            \
                hfifv.x = fmaf(tfi.x, fi.y, hfifv.x);                         \
                hfifv.y = fmaf(tfi.x, V,    hfifv.y);                         \
                const float tV = t * V;                                       \
                hvvv.x = fmaf(t,  V, hvvv.x);                                 \
                hvvv.y = fmaf(tV, V, hvvv.y);                                 \
            }                                                                 \
            __builtin_amdgcn_wave_barrier();  /* read->next-write */          \
            /* vertical ring: k=0 OVERWRITES slot P%11 (wipes phantom),      \
               k>=1 accumulates. All slot indices compile-time. */            \
            {                                                                 \
                const f32x2 w02 = (f32x2){w6[0], w6[0]};                      \
                acc[(P) % 11][0] = w02 * hfhi;                                \
                acc[(P) % 11][1] = w02 * hffii;                               \
                acc[(P) % 11][2] = w02 * hfifv;                               \
                acc[(P) % 11][3] = w02 * hvvv;                                \
            }                                                                 \
            _Pragma("unroll")                                                 \
            for (int k = 1; k < 11; ++k) {                                    \
                const int s = ((P) - k + 22) % 11;                            \
                const float t = w6[k < 6 ? k : 10 - k];                       \
                const f32x2 t2 = (f32x2){t, t};                               \
                acc[s][0] = __builtin_elementwise_fma(t2, hfhi,  acc[s][0]);  \
                acc[s][1] = __builtin_elementwise_fma(t2, hffii, acc[s][1]);  \
                acc[s][2] = __builtin_elementwise_fma(t2, hfifv, acc[s][2]);  \
                acc[s][3] = __builtin_elementwise_fma(t2, hvvv,  acc[s][3]);  \
            }                                                                 \
            /* finalize output row r-10 (slot just got its k=10 term) */      \
            if (r >= 10) {                                                    \
                const int s = ((P) + 1) % 11;                                 \
                const float mu1 = acc[s][0].x, mu2 = acc[s][0].y;             \
                const float mu3 = acc[s][3].x;                                \
                const float eff = acc[s][1].x, eii = acc[s][1].y;             \
                const float evv = acc[s][3].y;                                \
                const float efi = acc[s][2].x, efv = acc[s][2].y;             \
                const float mu1sq = mu1*mu1, mu2sq = mu2*mu2, mu3sq = mu3*mu3;\
                const float mu12 = mu1*mu2, mu13 = mu1*mu3;                   \
                const float sf  = eff - mu1sq;                                \
                const float si  = eii - mu2sq;                                \
                const float sv  = evv - mu3sq;                                \
                const float s12 = efi - mu12;                                 \
                const float s13 = efv - mu13;                                 \
                const float n1 = (2.f*mu12 + SSIM_C1) * (2.f*s12 + SSIM_C2);  \
                const float d1 = (mu1sq + mu2sq + SSIM_C1) * (sf + si + SSIM_C2); \
                const float n2 = (2.f*mu13 + SSIM_C1) * (2.f*s13 + SSIM_C2);  \
                const float d2 = (mu1sq + mu3sq + SSIM_C1) * (sf + sv + SSIM_C2); \
                const float q1 = __builtin_amdgcn_rcpf(d1);                   \
                const float q2 = __builtin_amdgcn_rcpf(d2);                   \
                if (col_ok) lssim += fmaf(n1, q1, n2 * q2);                   \
            }                                                                 \
        }                                                                     \
    }

// ---------------- Kernel A: fused double SSIM (separable 11x11 gaussian) ----
// Grid: (2 col blocks of 256, 16 row strips of 32, 32 batch) = 1024 blocks
// = 4 blocks/CU resident (VGPR 84 -> HW allows ~6 waves/SIMD; grid gives 4).
// Block = 4 independent waves; wave wv owns 64 cols; wave-private LDS rows.
// No __syncthreads in the main loop (in-order DS pipe within a wave;
// wave_barrier() fences compiler reordering, zero-cost).
__global__ __launch_bounds__(256, 2)
void ssim_kernel(const float* __restrict__ fus, const float* __restrict__ irp,
                 const float* __restrict__ vip, float* __restrict__ part,
                 GaussW gw)
{
    const int b    = blockIdx.z;
    const int r0   = blockIdx.y * 32;
    const int tid  = threadIdx.x;
    const int wv   = tid >> 6;          // wave 0..3
    const int lane = tid & 63;
    const int c0   = blockIdx.x * 256 + wv * 64;   // wave's column base
    const int out_rows = min(32, 502 - r0);        // last strip: 22
    const int in_rows  = out_rows + 10;            // <= 42

    const size_t ib = (size_t)b * 512 * 512;
    const float* __restrict__ Fp = fus + ib;
    const float* __restrict__ Ip = irp + ib;
    const float* __restrict__ Vp = vip + ib;

    __shared__ f32x2 srow_fi[4][80];    // wave-private {F,I} pairs
    __shared__ float srow_v [4][80];    // wave-private V

    float w6[6];                        // gaussian symmetric: w[k]=w[10-k]
#pragma unroll
    for (int k = 0; k < 6; ++k) w6[k] = gw.w[k];

    // register ring: 11 rows x 4 f32x2 pairs:
    //   [0]={hf,hi} [1]={hff,hii} [2]={hfi,hfv} [3]={hv,hvv}
    f32x2 acc[11][4];
#pragma unroll
    for (int s = 0; s < 11; ++s)
#pragma unroll
        for (int q = 0; q < 4; ++q) acc[s][q] = (f32x2)(0.f);

    float lssim = 0.f;
    const int  col      = c0 + lane;
    const bool col_ok   = col <= 501;             // valid output column
    const bool extra    = lane < 10;              // loads the 10-col halo
    const int  col2     = c0 + 64 + lane;
    const bool extra_ok = extra && (col2 < 512);

    // prologue: prefetch rows 0 and 1 into buffers A and B (in_rows >= 32)
    float arf, arg, arv, arf2 = 0.f, arg2 = 0.f, arv2 = 0.f;
    float brf, brg, brv, brf2 = 0.f, brg2 = 0.f, brv2 = 0.f;
    {
        const size_t b0 = (size_t)r0 * 512 + col;
        arf = Fp[b0]; arg = Ip[b0]; arv = Vp[b0];
        const size_t b1 = (size_t)(r0 + 1) * 512 + col;
        brf = Fp[b1]; brg = Ip[b1]; brv = Vp[b1];
        if (extra_ok) {
            const size_t c20 = (size_t)r0 * 512 + col2;
            arf2 = Fp[c20]; arg2 = Ip[c20]; arv2 = Vp[c20];
            const size_t c21 = (size_t)(r0 + 1) * 512 + col2;
            brf2 = Fp[c21]; brg2 = Ip[c21]; brv2 = Vp[c21];
        }
    }

#pragma unroll 1
    for (int rb = 0; rb < 44; rb += 22) {   // in_rows <= 42: exactly 2 iters
        SSIM_STEP(0,  arf, arg, arv, arf2, arg2, arv2)
        SSIM_STEP(1,  brf, brg, brv, brf2, brg2, brv2)
        SSIM_STEP(2,  arf, arg, arv, arf2, arg2, arv2)
        SSIM_STEP(3,  brf, brg, brv, brf2, brg2, brv2)
        SSIM_STEP(4,  arf, arg, arv, arf2, arg2, arv2)
        SSIM_STEP(5,  brf, brg, brv, brf2, brg2, brv2)
        SSIM_STEP(6,  arf, arg, arv, arf2, arg2, arv2)
        SSIM_STEP(7,  brf, brg, brv, brf2, brg2, brv2)
        SSIM_STEP(8,  arf, arg, arv, arf2, arg2, arv2)
        SSIM_STEP(9,  brf, brg, brv, brf2, brg2, brv2)
        SSIM_STEP(10, arf, arg, arv, arf2, arg2, arv2)
        SSIM_STEP(11, brf, brg, brv, brf2, brg2, brv2)
        SSIM_STEP(12, arf, arg, arv, arf2, arg2, arv2)
        SSIM_STEP(13, brf, brg, brv, brf2, brg2, brv2)
        SSIM_STEP(14, arf, arg, arv, arf2, arg2, arv2)
        SSIM_STEP(15, brf, brg, brv, brf2, brg2, brv2)
        SSIM_STEP(16, arf, arg, arv, arf2, arg2, arv2)
        SSIM_STEP(17, brf, brg, brv, brf2, brg2, brv2)
        SSIM_STEP(18, arf, arg, arv, arf2, arg2, arv2)
        SSIM_STEP(19, brf, brg, brv, brf2, brg2, brv2)
        SSIM_STEP(20, arf, arg, arv, arf2, arg2, arv2)
        SSIM_STEP(21, brf, brg, brv, brf2, brg2, brv2)
    }

    // cross-wave block reduction -> one partial write (no atomic)
#pragma unroll
    for (int off = 32; off > 0; off >>= 1)
        lssim += __shfl_down(lssim, off);
    __shared__ float red[4];
    if (lane == 0) red[wv] = lssim;
    __syncthreads();
    if (tid == 0) {
        const int blk = blockIdx.x + 2 * (blockIdx.y + 16 * blockIdx.z); // 0..1023
        part[blk] = red[0] + red[1] + red[2] + red[3];
    }
}

// ---------------- Kernel B: L1 + laplacian grad loss ------------------------
__device__ inline float4 lap3x3(const float* __restrict__ rm,
                                const float* __restrict__ rc,
                                const float* __restrict__ rp,
                                int x0, int xl, int xr, float4& center)
{
    float4 a = *(const float4*)(rm + x0);
    float4 b = *(const float4*)(rc + x0);
    float4 c = *(const float4*)(rp + x0);
    const float aL = rm[xl], bL = rc[xl], cL = rp[xl];
    const float aR = rm[xr], bR = rc[xr], cR = rp[xr];
    const float s0 = aL + bL + cL;
    const float s1 = a.x + b.x + c.x;
    const float s2 = a.y + b.y + c.y;
    const float s3 = a.z + b.z + c.z;
    const float s4 = a.w + b.w + c.w;
    const float s5 = aR + bR + cR;
    center = b;
    float4 l;
    l.x = (s0 + s1 + s2 - 9.f*b.x) * 0.0625f;
    l.y = (s1 + s2 + s3 - 9.f*b.y) * 0.0625f;
    l.z = (s2 + s3 + s4 - 9.f*b.z) * 0.0625f;
    l.w = (s3 + s4 + s5 - 9.f*b.w) * 0.0625f;
    return l;
}

// Grid: dim3(64, 32) = 2048 blocks; each block covers 8 rows of one batch
// image (4 iterations x 2 rows). Partial sums to d_ws, no atomics.
__global__ __launch_bounds__(256, 4)
void lapl1_kernel(const float* __restrict__ fus, const float* __restrict__ irp,
                  const float* __restrict__ vip, const float* __restrict__ mir,
                  const float* __restrict__ mvi,
                  float* __restrict__ part_l1, float* __restrict__ part_gr)
{
    const int b   = blockIdx.y;
    const int tid = threadIdx.x;
    const int xq  = tid & 127;
    const int x0  = xq * 4;
    const size_t ib = (size_t)b * 512 * 512;

    const int xl = (x0 == 0)        ? 1   : x0 - 1;   // reflect padding (x)
    const int xr = (x0 + 4 == 512)  ? 510 : x0 + 4;

    const float* Fb = fus + ib;
    const float* Ib = irp + ib;
    const float* Vb = vip + ib;

    float l1s = 0.f, grs = 0.f;

#pragma unroll
    for (int it = 0; it < 4; ++it) {
        const int y  = blockIdx.x * 8 + it * 2 + (tid >> 7);
        const int ym = (y == 0)   ? 1   : y - 1;       // reflect padding (y)
        const int yp = (y == 511) ? 510 : y + 1;

        float4 cf, ci, cv;
        const float4 lf = lap3x3(Fb + (size_t)ym*512, Fb + (size_t)y*512, Fb + (size_t)yp*512, x0, xl, xr, cf);
        const float4 li = lap3x3(Ib + (size_t)ym*512, Ib + (size_t)y*512, Ib + (size_t)yp*512, x0, xl, xr, ci);
        const float4 lv = lap3x3(Vb + (size_t)ym*512, Vb + (size_t)y*512, Vb + (size_t)yp*512, x0, xl, xr, cv);

        const float4 m1 = *(const float4*)(mir + ib + (size_t)y*512 + x0);
        const float4 m2 = *(const float4*)(mvi + ib + (size_t)y*512 + x0);

        l1s += fabsf(fmaxf(m1.x, m2.x) - cf.x) + fabsf(fmaxf(m1.y, m2.y) - cf.y)
             + fabsf(fmaxf(m1.z, m2.z) - cf.z) + fabsf(fmaxf(m1.w, m2.w) - cf.w);

        grs += fabsf(fmaxf(fabsf(li.x), fabsf(lv.x)) - fabsf(lf.x))
             + fabsf(fmaxf(fabsf(li.y), fabsf(lv.y)) - fabsf(lf.y))
             + fabsf(fmaxf(fabsf(li.z), fabsf(lv.z)) - fabsf(lf.z))
             + fabsf(fmaxf(fabsf(li.w), fabsf(lv.w)) - fabsf(lf.w));
    }

#pragma unroll
    for (int off = 32; off > 0; off >>= 1) {
        l1s += __shfl_down(l1s, off);
        grs += __shfl_down(grs, off);
    }
    __shared__ float red[8];
    if ((tid & 63) == 0) { red[tid >> 6] = l1s; red[4 + (tid >> 6)] = grs; }
    __syncthreads();
    if (tid == 0) {
        const int blk = blockIdx.x + 64 * blockIdx.y;  // 0..2047
        part_l1[blk] = red[0] + red[1] + red[2] + red[3];
        part_gr[blk] = red[4] + red[5] + red[6] + red[7];
    }
}

// ---------------- final combine: reduce all partials ------------------------
__global__ void final_kernel(const float* __restrict__ ws, float* __restrict__ out)
{
    const int tid = threadIdx.x;
    float s0 = 0.f, s1 = 0.f, s2 = 0.f;
#pragma unroll
    for (int i = tid; i < 1024; i += 256) s0 += ws[i];
#pragma unroll
    for (int i = tid; i < 2048; i += 256) {
        s1 += ws[1024 + i];
        s2 += ws[3072 + i];
    }
#pragma unroll
    for (int off = 32; off > 0; off >>= 1) {
        s0 += __shfl_down(s0, off);
        s1 += __shfl_down(s1, off);
        s2 += __shfl_down(s2, off);
    }
    __shared__ float red[12];
    if ((tid & 63) == 0) {
        red[tid >> 6] = s0; red[4 + (tid >> 6)] = s1; red[8 + (tid >> 6)] = s2;
    }
    __syncthreads();
    if (tid == 0) {
        const float ssim_sum = red[0] + red[1] + red[2] + red[3];
        const float l1_sum   = red[4] + red[5] + red[6] + red[7];
        const float gr_sum   = red[8] + red[9] + red[10] + red[11];
        const float ms = 2.f - ssim_sum / 8064128.f;   // 32*502*502
        const float l1 = l1_sum / 8388608.f;           // 32*512*512
        const float gr = gr_sum / 8388608.f;
        out[0] = ms + l1 + 10.f * gr;
    }
}

extern "C" void kernel_launch(void* const* d_in, const int* in_sizes, int n_in,
                              void* d_out, int out_size, void* d_ws, size_t ws_size,
                              hipStream_t stream)
{
    const float* fus = (const float*)d_in[0];
    const float* irp = (const float*)d_in[1];
    const float* vip = (const float*)d_in[2];
    const float* mir = (const float*)d_in[3];
    const float* mvi = (const float*)d_in[4];
    float* out = (float*)d_out;
    float* ws  = (float*)d_ws;

    // gaussian window (matches np: f64 normalize, cast to f32)
    GaussW gw;
    double g[11], s = 0.0;
    for (int i = 0; i < 11; ++i) {
        const double d = (double)i - 5.0;
        g[i] = std::exp(-(d * d) / (2.0 * 1.5 * 1.5));
        s += g[i];
    }
    for (int i = 0; i < 11; ++i) gw.w[i] = (float)(g[i] / s);

    ssim_kernel<<<dim3(2, 16, 32), 256, 0, stream>>>(fus, irp, vip, ws, gw);
    lapl1_kernel<<<dim3(64, 32), 256, 0, stream>>>(fus, irp, vip, mir, mvi,
                                                   ws + 1024, ws + 3072);
    final_kernel<<<1, 256, 0, stream>>>(ws, out);
}

// Round 14
// 103.772 us; speedup vs baseline: 1.1619x; 1.1619x over previous
//
#include <hip/hip_runtime.h>
#include <cmath>

// FusionLoss = ms_ssim(fus,ir)+ms_ssim(fus,vi) + l1(max(map_ir,map_vi),fus)
//            + 10*mean(|max(|lap ir|,|lap vi|) - |lap fus||)
// Inputs: im_fus, im_ir, im_vi, map_ir, map_vi  each [32,1,512,512] fp32.
//
// d_ws layout (floats): [0..768)     ssim partials
//                       [768..1536)  l1 partials
//                       [1536..2304) grad partials   (all from the 768 blocks)
//
// Journal: r2 atomics->partials. Spills: r5/r8/r10/r13 (VGPR caps; b128 quads;
// 4-blocks/CU never fits: HW holds 3 blocks/CU of this kernel -> 768-block
// grid is THE geometry). r9/r12 best: pk-f32 pairs, ssim 72.9us @ VGPR 84,
// total 110.8. r11 side-by-side fusion NEG (HBM contention between block
// types). r14: ride the L1+laplacian INSIDE the ssim row pipeline — the
// rows of F,I,V already stream through LDS; a 3x3 laplacian needs only a
// 3-deep colsum register history (+~21 VALU, +4 DS reads, +2 global/row)
// and the whole 33us lapl1 kernel disappears. Laplacians kept 16x-unscaled;
// 1/16 folded into the partial write. Row coverage: strip rs owns lapl rows
// 42rs+1..42rs+42; strip0 adds row 0 (reflect); strip11 extends to 511
// (epilogue). 43 + 10*42 + 49 = 512 rows exactly once.
// GUARDS: VGPR<=120, WRITE<=50KB else spill -> revert to r12.

typedef float f32x2 __attribute__((ext_vector_type(2)));

struct GaussW { float w[11]; };

#define SSIM_C1 1.0e-4f
#define SSIM_C2 9.0e-4f

// One row step. P is a literal 0..21: ring slots, parity, and the lapl
// row-range conditions (r==1, r<=43) all fold at compile time.
#define SSIM_STEP(P, RF, RG, RV, RF2, RG2, RV2, RFL, RGL, RVL, RM1, RM2)      \
    {                                                                         \
        const int r = rb + (P);                                               \
        if (r < in_rows) {   /* wave-uniform guard */                         \
            const float curF = RF, curI = RG, curV = RV;                      \
            /* stage row r */                                                 \
            srow_fi[wv][lane] = (f32x2){RF, RG};                              \
            srow_v [wv][lane] = RV;                                           \
            if (extra)  { srow_fi[wv][64 + lane] = (f32x2){RF2, RG2};         \
                          srow_v [wv][64 + lane] = RV2; }                     \
            if (extraL) { srow_fi[wv][74] = (f32x2){RFL, RGL};                \
                          srow_v [wv][74] = RVL; }                            \
            __builtin_amdgcn_wave_barrier();  /* write->read order */         \
            /* depth-2 prefetch of row r+2 (main + right halo + left halo) */ \
            if (r + 2 < in_rows) {                                            \
                const size_t base = (size_t)(r0 + r + 2) * 512 + col;         \
                RF = Fp[base]; RG = Ip[base]; RV = Vp[base];                  \
                if (extra_ok) {                                               \
                    const size_t b2 = (size_t)(r0 + r + 2) * 512 + col2;      \
                    RF2 = Fp[b2]; RG2 = Ip[b2]; RV2 = Vp[b2];                 \
                }                                                             \
                if (extraL) {                                                 \
                    const size_t bl = (size_t)(r0 + r + 2) * 512 + colL;      \
                    RFL = Fp[bl]; RGL = Ip[bl]; RVL = Vp[bl];                 \
                }                                                             \
            }                                                                 \
            /* mir/mvi: use pair loaded 2 steps ago; prefetch for step r+2 */ \
            const float um1 = RM1, um2 = RM2;                                 \
            if (((r + 2) <= 43 || last) && (r + 2) < in_rows) {               \
                const size_t bm = (size_t)(r0 + r + 1) * 512 + col;           \
                RM1 = mir[bm]; RM2 = mvi[bm];                                 \
            }                                                                 \
            /* horizontal gaussian sums, packed-f32 where pairable */         \
            f32x2 hfhi  = (f32x2)(0.f);                                       \
            f32x2 hffii = (f32x2)(0.f);                                       \
            f32x2 hfifv = (f32x2)(0.f);                                       \
            f32x2 hvvv  = (f32x2)(0.f);                                       \
            _Pragma("unroll")                                                 \
            for (int k = 0; k < 11; ++k) {                                    \
                const float t = w6[k < 6 ? k : 10 - k];                       \
                const f32x2 fi = srow_fi[wv][lane + k];                       \
                const float V  = srow_v [wv][lane + k];                       \
                const f32x2 t2 = (f32x2){t, t};                               \
                const f32x2 tfi = t2 * fi;                                    \
                hfhi  = __builtin_elementwise_fma(t2,  fi, hfhi);             \
                hffii = __builtin_elementwise_fma(tfi, fi, hffii);            \
                hfifv.x = fmaf(tfi.x, fi.y, hfifv.x);                         \
                hfifv.y = fmaf(tfi.x, V,    hfifv.y);                         \
                const float tV = t * V;                                       \
                hvvv.x = fmaf(t,  V, hvvv.x);                                 \
                hvvv.y = fmaf(tV, V, hvvv.y);                                 \
            }                                                                 \
            /* 3-col sums for the laplacian (reads staged row at l-1, l+1) */ \
            f32x2 csFI_cur = (f32x2)(0.f); float csV_cur = 0.f;               \
            if ((rb + (P)) <= 43 || last) {                                   \
                const f32x2 fiL = srow_fi[wv][il];                            \
                const f32x2 fiR = srow_fi[wv][ir_];                           \
                const float vsL = srow_v[wv][il];                             \
                const float vsR = srow_v[wv][ir_];                            \
                csFI_cur = fiL + fiR + (f32x2){curF, curI};                   \
                csV_cur  = vsL + vsR + curV;                                  \
            }                                                                 \
            __builtin_amdgcn_wave_barrier();  /* read->next-write */          \
            /* vertical ring: k=0 OVERWRITES slot P%11, k>=1 accumulates */   \
            {                                                                 \
                const f32x2 w02 = (f32x2){w6[0], w6[0]};                      \
                acc[(P) % 11][0] = w02 * hfhi;                                \
                acc[(P) % 11][1] = w02 * hffii;                               \
                acc[(P) % 11][2] = w02 * hfifv;                               \
                acc[(P) % 11][3] = w02 * hvvv;                                \
            }                                                                 \
            _Pragma("unroll")                                                 \
            for (int k = 1; k < 11; ++k) {                                    \
                const int s = ((P) - k + 22) % 11;                            \
                const float t = w6[k < 6 ? k : 10 - k];                       \
                const f32x2 t2 = (f32x2){t, t};                               \
                acc[s][0] = __builtin_elementwise_fma(t2, hfhi,  acc[s][0]);  \
                acc[s][1] = __builtin_elementwise_fma(t2, hffii, acc[s][1]);  \
                acc[s][2] = __builtin_elementwise_fma(t2, hfifv, acc[s][2]);  \
                acc[s][3] = __builtin_elementwise_fma(t2, hvvv,  acc[s][3]);  \
            }                                                                 \
            /* ssim finalize output row r-10 */                               \
            if (r >= 10) {                                                    \
                const int s = ((P) + 1) % 11;                                 \
                const float mu1 = acc[s][0].x, mu2 = acc[s][0].y;             \
                const float mu3 = acc[s][3].x;                                \
                const float eff = acc[s][1].x, eii = acc[s][1].y;             \
                const float evv = acc[s][3].y;                                \
                const float efi = acc[s][2].x, efv = acc[s][2].y;             \
                const float mu1sq = mu1*mu1, mu2sq = mu2*mu2, mu3sq = mu3*mu3;\
                const float mu12 = mu1*mu2, mu13 = mu1*mu3;                   \
                const float sf  = eff - mu1sq;                                \
                const float si  = eii - mu2sq;                                \
                const float sv  = evv - mu3sq;                                \
                const float s12 = efi - mu12;                                 \
                const float s13 = efv - mu13;                                 \
                const float n1 = (2.f*mu12 + SSIM_C1) * (2.f*s12 + SSIM_C2);  \
                const float d1 = (mu1sq + mu2sq + SSIM_C1) * (sf + si + SSIM_C2); \
                const float n2 = (2.f*mu13 + SSIM_C1) * (2.f*s13 + SSIM_C2);  \
                const float d2 = (mu1sq + mu3sq + SSIM_C1) * (sf + sv + SSIM_C2); \
                const float q1 = __builtin_amdgcn_rcpf(d1);                   \
                const float q2 = __builtin_amdgcn_rcpf(d2);                   \
                if (col_ok) lssim += fmaf(n1, q1, n2 * q2);                   \
            }                                                                 \
            /* laplacian + l1 for global row y = r0 + r - 1 (16x-unscaled) */ \
            if (r >= 2 && ((rb + (P)) <= 43 || last)) {                       \
                const f32x2 sFI = csFI_2 + csFI_1 + csFI_cur;                 \
                const float sV  = csV_2 + csV_1 + csV_cur;                    \
                const f32x2 lFI = __builtin_elementwise_fma(                  \
                                     (f32x2){-9.f,-9.f}, cPrevFI, sFI);       \
                const float lV  = fmaf(-9.f, cPrevV, sV);                     \
                grs += fabsf(fmaxf(fabsf(lFI.y), fabsf(lV)) - fabsf(lFI.x));  \
                l1s += fabsf(fmaxf(um1, um2) - cPrevFI.x);                    \
            }                                                                 \
            if (first && (rb + (P)) == 1) {  /* y = 0, reflect row -1 -> 1 */ \
                const f32x2 sFI = csFI_1 + csFI_cur + csFI_cur;               \
                const float sV  = csV_1 + csV_cur + csV_cur;                  \
                const f32x2 lFI = __builtin_elementwise_fma(                  \
                                     (f32x2){-9.f,-9.f}, cPrevFI, sFI);       \
                const float lV  = fmaf(-9.f, cPrevV, sV);                     \
                grs += fabsf(fmaxf(fabsf(lFI.y), fabsf(lV)) - fabsf(lFI.x));  \
                l1s += fabsf(fmaxf(um1, um2) - cPrevFI.x);                    \
            }                                                                 \
            /* shift colsum/center history */                                 \
            if ((rb + (P)) <= 43 || last) {                                   \
                csFI_2 = csFI_1; csFI_1 = csFI_cur;                           \
                csV_2  = csV_1;  csV_1  = csV_cur;                            \
                cPrevFI = (f32x2){curF, curI}; cPrevV = curV;                 \
            }                                                                 \
        }                                                                     \
    }

// ---------------- fused SSIM + L1 + laplacian kernel ------------------------
// Grid: (2 col blocks of 256, 12 row strips of 42, 32 batch) = 768 blocks
// = 3 blocks/CU resident in ONE round (HW ceiling for this kernel).
// Block = 4 independent waves; wave wv owns 64 cols; wave-private LDS rows;
// no __syncthreads in the main loop (in-order DS pipe within a wave).
__global__ __launch_bounds__(256, 2)
void ssim_kernel(const float* __restrict__ fus, const float* __restrict__ irp,
                 const float* __restrict__ vip, const float* __restrict__ mir,
                 const float* __restrict__ mvi, float* __restrict__ ws,
                 GaussW gw)
{
    const int b    = blockIdx.z;
    const int rs   = blockIdx.y;
    const int r0   = rs * 42;
    const int tid  = threadIdx.x;
    const int wv   = tid >> 6;          // wave 0..3
    const int lane = tid & 63;
    const int c0   = blockIdx.x * 256 + wv * 64;   // wave's column base
    const int out_rows = min(42, 502 - r0);        // last strip: 40
    const int in_rows  = out_rows + 10;            // 50..52
    const bool first = (rs == 0);
    const bool last  = (rs == 11);

    const size_t ib = (size_t)b * 512 * 512;
    const float* __restrict__ Fp = fus + ib;
    const float* __restrict__ Ip = irp + ib;
    const float* __restrict__ Vp = vip + ib;
    mir += ib;
    mvi += ib;

    __shared__ f32x2 srow_fi[4][80];    // [0..63] cols, [64..73] right halo, [74] left halo
    __shared__ float srow_v [4][80];

    float w6[6];                        // gaussian symmetric: w[k]=w[10-k]
#pragma unroll
    for (int k = 0; k < 6; ++k) w6[k] = gw.w[k];

    f32x2 acc[11][4];                   // ring: [0]={hf,hi} [1]={hff,hii} [2]={hfi,hfv} [3]={hv,hvv}
#pragma unroll
    for (int s = 0; s < 11; ++s)
#pragma unroll
        for (int q = 0; q < 4; ++q) acc[s][q] = (f32x2)(0.f);

    float lssim = 0.f, l1s = 0.f, grs = 0.f;
    const int  col      = c0 + lane;
    const bool col_ok   = col <= 501;             // ssim-valid output column
    const bool extra    = lane < 10;              // right 10-col halo loader
    const int  col2     = c0 + 64 + lane;
    const bool extra_ok = extra && (col2 < 512);
    const bool extraL   = (lane == 10) && (c0 > 0);  // left 1-col halo loader
    const int  colL     = c0 - 1;
    // per-lane neighbor LDS indices (reflect at image edges)
    const int il  = (lane == 0)  ? ((c0 == 0) ? 1 : 74) : (lane - 1);
    const int ir_ = (lane == 63) ? ((c0 + 64 >= 512) ? 62 : 64) : (lane + 1);

    // laplacian history
    f32x2 csFI_1 = (f32x2)(0.f), csFI_2 = (f32x2)(0.f);
    float csV_1 = 0.f, csV_2 = 0.f;
    f32x2 cPrevFI = (f32x2)(0.f); float cPrevV = 0.f;

    // prologue: prefetch rows 0,1 (A/B) incl. halos; mB = mir/mvi row r0
    float arf, arg, arv, arf2 = 0.f, arg2 = 0.f, arv2 = 0.f;
    float brf, brg, brv, brf2 = 0.f, brg2 = 0.f, brv2 = 0.f;
    float aRFL = 0.f, aRGL = 0.f, aRVL = 0.f;
    float bRFL = 0.f, bRGL = 0.f, bRVL = 0.f;
    float mA1 = 0.f, mA2 = 0.f, mB1, mB2;
    {
        const size_t b0 = (size_t)r0 * 512 + col;
        arf = Fp[b0]; arg = Ip[b0]; arv = Vp[b0];
        const size_t b1 = (size_t)(r0 + 1) * 512 + col;
        brf = Fp[b1]; brg = Ip[b1]; brv = Vp[b1];
        if (extra_ok) {
            const size_t c20 = (size_t)r0 * 512 + col2;
            arf2 = Fp[c20]; arg2 = Ip[c20]; arv2 = Vp[c20];
            const size_t c21 = (size_t)(r0 + 1) * 512 + col2;
            brf2 = Fp[c21]; brg2 = Ip[c21]; brv2 = Vp[c21];
        }
        if (extraL) {
            const size_t l0 = (size_t)r0 * 512 + colL;
            aRFL = Fp[l0]; aRGL = Ip[l0]; aRVL = Vp[l0];
            const size_t l1x = (size_t)(r0 + 1) * 512 + colL;
            bRFL = Fp[l1x]; bRGL = Ip[l1x]; bRVL = Vp[l1x];
        }
        const size_t bm = (size_t)r0 * 512 + col;   // row r0 (used at step 1 if first)
        mB1 = mir[bm]; mB2 = mvi[bm];
    }

#pragma unroll 1
    for (int rb = 0; rb < 66; rb += 22) {
        SSIM_STEP(0,  arf, arg, arv, arf2, arg2, arv2, aRFL, aRGL, aRVL, mA1, mA2)
        SSIM_STEP(1,  brf, brg, brv, brf2, brg2, brv2, bRFL, bRGL, bRVL, mB1, mB2)
        SSIM_STEP(2,  arf, arg, arv, arf2, arg2, arv2, aRFL, aRGL, aRVL, mA1, mA2)
        SSIM_STEP(3,  brf, brg, brv, brf2, brg2, brv2, bRFL, bRGL, bRVL, mB1, mB2)
        SSIM_STEP(4,  arf, arg, arv, arf2, arg2, arv2, aRFL, aRGL, aRVL, mA1, mA2)
        SSIM_STEP(5,  brf, brg, brv, brf2, brg2, brv2, bRFL, bRGL, bRVL, mB1, mB2)
        SSIM_STEP(6,  arf, arg, arv, arf2, arg2, arv2, aRFL, aRGL, aRVL, mA1, mA2)
        SSIM_STEP(7,  brf, brg, brv, brf2, brg2, brv2, bRFL, bRGL, bRVL, mB1, mB2)
        SSIM_STEP(8,  arf, arg, arv, arf2, arg2, arv2, aRFL, aRGL, aRVL, mA1, mA2)
        SSIM_STEP(9,  brf, brg, brv, brf2, brg2, brv2, bRFL, bRGL, bRVL, mB1, mB2)
        SSIM_STEP(10, arf, arg, arv, arf2, arg2, arv2, aRFL, aRGL, aRVL, mA1, mA2)
        SSIM_STEP(11, brf, brg, brv, brf2, brg2, brv2, bRFL, bRGL, bRVL, mB1, mB2)
        SSIM_STEP(12, arf, arg, arv, arf2, arg2, arv2, aRFL, aRGL, aRVL, mA1, mA2)
        SSIM_STEP(13, brf, brg, brv, brf2, brg2, brv2, bRFL, bRGL, bRVL, mB1, mB2)
        SSIM_STEP(14, arf, arg, arv, arf2, arg2, arv2, aRFL, aRGL, aRVL, mA1, mA2)
        SSIM_STEP(15, brf, brg, brv, brf2, brg2, brv2, bRFL, bRGL, bRVL, mB1, mB2)
        SSIM_STEP(16, arf, arg, arv, arf2, arg2, arv2, aRFL, aRGL, aRVL, mA1, mA2)
        SSIM_STEP(17, brf, brg, brv, brf2, brg2, brv2, bRFL, bRGL, bRVL, mB1, mB2)
        SSIM_STEP(18, arf, arg, arv, arf2, arg2, arv2, aRFL, aRGL, aRVL, mA1, mA2)
        SSIM_STEP(19, brf, brg, brv, brf2, brg2, brv2, bRFL, bRGL, bRVL, mB1, mB2)
        SSIM_STEP(20, arf, arg, arv, arf2, arg2, arv2, aRFL, aRGL, aRVL, mA1, mA2)
        SSIM_STEP(21, brf, brg, brv, brf2, brg2, brv2, bRFL, bRGL, bRVL, mB1, mB2)
    }

    // epilogue: last strip handles global row 511 (reflect row 512 -> 510)
    if (last) {
        const size_t bm = (size_t)511 * 512 + col;
        const float m1e = mir[bm], m2e = mvi[bm];
        const f32x2 sFI = csFI_2 + csFI_2 + csFI_1;
        const float sV  = csV_2 + csV_2 + csV_1;
        const f32x2 lFI = __builtin_elementwise_fma((f32x2){-9.f,-9.f}, cPrevFI, sFI);
        const float lV  = fmaf(-9.f, cPrevV, sV);
        grs += fabsf(fmaxf(fabsf(lFI.y), fabsf(lV)) - fabsf(lFI.x));
        l1s += fabsf(fmaxf(m1e, m2e) - cPrevFI.x);
    }

    // cross-wave block reduction -> three partial writes (no atomics)
#pragma unroll
    for (int off = 32; off > 0; off >>= 1) {
        lssim += __shfl_down(lssim, off);
        l1s   += __shfl_down(l1s, off);
        grs   += __shfl_down(grs, off);
    }
    __shared__ float red[12];
    if (lane == 0) { red[wv] = lssim; red[4 + wv] = l1s; red[8 + wv] = grs; }
    __syncthreads();
    if (tid == 0) {
        const int blk = blockIdx.x + 2 * (blockIdx.y + 12 * blockIdx.z); // 0..767
        ws[blk]        = red[0] + red[1] + red[2] + red[3];
        ws[768 + blk]  = red[4] + red[5] + red[6] + red[7];
        ws[1536 + blk] = (red[8] + red[9] + red[10] + red[11]) * 0.0625f; // /16
    }
}

// ---------------- final combine: reduce all partials ------------------------
__global__ void final_kernel(const float* __restrict__ ws, float* __restrict__ out)
{
    const int tid = threadIdx.x;
    float s0 = 0.f, s1 = 0.f, s2 = 0.f;
#pragma unroll
    for (int i = tid; i < 768; i += 256) {
        s0 += ws[i];
        s1 += ws[768 + i];
        s2 += ws[1536 + i];
    }
#pragma unroll
    for (int off = 32; off > 0; off >>= 1) {
        s0 += __shfl_down(s0, off);
        s1 += __shfl_down(s1, off);
        s2 += __shfl_down(s2, off);
    }
    __shared__ float red[12];
    if ((tid & 63) == 0) {
        red[tid >> 6] = s0; red[4 + (tid >> 6)] = s1; red[8 + (tid >> 6)] = s2;
    }
    __syncthreads();
    if (tid == 0) {
        const float ssim_sum = red[0] + red[1] + red[2] + red[3];
        const float l1_sum   = red[4] + red[5] + red[6] + red[7];
        const float gr_sum   = red[8] + red[9] + red[10] + red[11];
        const float ms = 2.f - ssim_sum / 8064128.f;   // 32*502*502
        const float l1 = l1_sum / 8388608.f;           // 32*512*512
        const float gr = gr_sum / 8388608.f;
        out[0] = ms + l1 + 10.f * gr;
    }
}

extern "C" void kernel_launch(void* const* d_in, const int* in_sizes, int n_in,
                              void* d_out, int out_size, void* d_ws, size_t ws_size,
                              hipStream_t stream)
{
    const float* fus = (const float*)d_in[0];
    const float* irp = (const float*)d_in[1];
    const float* vip = (const float*)d_in[2];
    const float* mir = (const float*)d_in[3];
    const float* mvi = (const float*)d_in[4];
    float* out = (float*)d_out;
    float* ws  = (float*)d_ws;

    // gaussian window (matches np: f64 normalize, cast to f32)
    GaussW gw;
    double g[11], s = 0.0;
    for (int i = 0; i < 11; ++i) {
        const double d = (double)i - 5.0;
        g[i] = std::exp(-(d * d) / (2.0 * 1.5 * 1.5));
        s += g[i];
    }
    for (int i = 0; i < 11; ++i) gw.w[i] = (float)(g[i] / s);

    ssim_kernel<<<dim3(2, 12, 32), 256, 0, stream>>>(fus, irp, vip, mir, mvi,
                                                     ws, gw);
    final_kernel<<<1, 256, 0, stream>>>(ws, out);
}

// Round 15
// 96.467 us; speedup vs baseline: 1.2499x; 1.0757x over previous
//
#include <hip/hip_runtime.h>
#include <cmath>

// FusionLoss = ms_ssim(fus,ir)+ms_ssim(fus,vi) + l1(max(map_ir,map_vi),fus)
//            + 10*mean(|max(|lap ir|,|lap vi|) - |lap fus||)
// Inputs: im_fus, im_ir, im_vi, map_ir, map_vi  each [32,1,512,512] fp32.
//
// d_ws layout (floats): [0..768) ssim | [768..1536) l1 | [1536..2304) grad
//
// Journal: r2 atomics->partials. r9/r12 pk-f32 ssim 72.9us @ VGPR 84.
// r14 lapl riding inside ssim pipeline: total 110.8->103.8 (best) but
// VGPR 104, fused ~100us. Pipe model: per-CU DS pipe (~45us) >> VALU
// (~26us) is the floor; kernel is DS-latency bound. r15: depth-1 loop
// (r12 proved depth-2 neutral, -6 reg), unified halo prefetch (-3 reg),
// lapl right-neighbor = gaussian k=1 tap (lapl DS reads 4->2/row),
// mir/mvi 1-step reg prefetch. Same 768-block/42-row geometry.
// GUARDS: VGPR<=100, WRITE<=50KB else revert to r14.

typedef float f32x2 __attribute__((ext_vector_type(2)));

struct GaussW { float w[11]; };

#define SSIM_C1 1.0e-4f
#define SSIM_C2 9.0e-4f

// ---------------- fused SSIM + L1 + laplacian kernel ------------------------
// Grid: (2 col blocks of 256, 12 row strips of 42, 32 batch) = 768 blocks
// = 3 blocks/CU resident. Block = 4 independent waves; wave wv owns 64 cols;
// wave-private LDS rows; no __syncthreads in the main loop (in-order DS pipe
// within a wave; wave_barrier() fences compiler reordering).
// Vertical gaussian: 11-slot register ring; slot (o mod 11) OVERWRITTEN by
// the k=0 term when output row o begins (wipes phantom o<0 garbage).
// Laplacian rides the row sweep: 3-deep column-sum register history;
// strip rs owns lapl rows 42rs+1..42rs+42 (strip0 adds y=0 reflect;
// strip11 extends to 510 + epilogue 511). 43+10*42+48+1 = 512 rows once.
__global__ __launch_bounds__(256, 2)
void ssim_kernel(const float* __restrict__ fus, const float* __restrict__ irp,
                 const float* __restrict__ vip, const float* __restrict__ mir,
                 const float* __restrict__ mvi, float* __restrict__ ws,
                 GaussW gw)
{
    const int b    = blockIdx.z;
    const int rs   = blockIdx.y;
    const int r0   = rs * 42;
    const int tid  = threadIdx.x;
    const int wv   = tid >> 6;          // wave 0..3
    const int lane = tid & 63;
    const int c0   = blockIdx.x * 256 + wv * 64;   // wave's column base
    const int out_rows = min(42, 502 - r0);        // last strip: 40
    const int in_rows  = out_rows + 10;            // 50..52
    const bool first = (rs == 0);
    const bool last  = (rs == 11);

    const size_t ib = (size_t)b * 512 * 512;
    const float* __restrict__ Fp = fus + ib;
    const float* __restrict__ Ip = irp + ib;
    const float* __restrict__ Vp = vip + ib;
    mir += ib;
    mvi += ib;

    __shared__ f32x2 srow_fi[4][80];    // [0..63] cols, [64..73] right halo, [74] left halo
    __shared__ float srow_v [4][80];

    float w6[6];                        // gaussian symmetric: w[k]=w[10-k]
#pragma unroll
    for (int k = 0; k < 6; ++k) w6[k] = gw.w[k];

    f32x2 acc[11][4];                   // ring: [0]={hf,hi} [1]={hff,hii} [2]={hfi,hfv} [3]={hv,hvv}
#pragma unroll
    for (int s = 0; s < 11; ++s)
#pragma unroll
        for (int q = 0; q < 4; ++q) acc[s][q] = (f32x2)(0.f);

    float lssim = 0.f, l1s = 0.f, grs = 0.f;
    const int  col      = c0 + lane;
    const bool col_ok   = col <= 501;             // ssim-valid output column
    // unified halo loader: lanes 0..9 -> right halo cols c0+64..c0+73,
    // lane 10 -> left halo col c0-1 (stored at LDS index 74 = 64+10).
    const bool is_left  = (lane == 10);
    const int  colH     = is_left ? (c0 - 1) : (c0 + 64 + lane);
    const bool halo_ok  = (lane < 10) ? (colH < 512) : (is_left && c0 > 0);
    const int  hidx     = 64 + lane;              // lane10 -> 74
    // lapl neighbor LDS indices (reflect at image edges)
    const int il       = (lane == 0) ? ((c0 == 0) ? 1 : 74) : (lane - 1);
    const bool rt_edge = (lane == 63) && (c0 + 64 >= 512);  // col 511: right=reflect(512)=510=left

    // laplacian history (column sums of rows r-1, r-2; center of row r-1)
    f32x2 csFI_1 = (f32x2)(0.f), csFI_2 = (f32x2)(0.f);
    float csV_1 = 0.f, csV_2 = 0.f;
    f32x2 cPrevFI = (f32x2)(0.f); float cPrevV = 0.f;
    float m1r = 0.f, m2r = 0.f;         // mir/mvi for row r0+r-1 (prefetch-by-1)

    // prologue: prefetch row 0 (main + unified halo)
    float rf, rg, rv, rf2 = 0.f, rg2 = 0.f, rv2 = 0.f;
    {
        const size_t b0 = (size_t)r0 * 512 + col;
        rf = Fp[b0]; rg = Ip[b0]; rv = Vp[b0];
        if (halo_ok) {
            const size_t bh = (size_t)r0 * 512 + colH;
            rf2 = Fp[bh]; rg2 = Ip[bh]; rv2 = Vp[bh];
        }
    }

#pragma unroll 1
    for (int rb = 0; rb < 55; rb += 11) {
#pragma unroll
        for (int p = 0; p < 11; ++p) {
            const int r = rb + p;                 // input row within strip
            if (r < in_rows) {                    // wave-uniform guard
                const float curF = rf, curI = rg, curV = rv;
                // stage row r (b64 pair + b32 V, + unified halo)
                srow_fi[wv][lane] = (f32x2){rf, rg};
                srow_v [wv][lane] = rv;
                if (halo_ok) {
                    srow_fi[wv][hidx] = (f32x2){rf2, rg2};
                    srow_v [wv][hidx] = rv2;
                }
                __builtin_amdgcn_wave_barrier();  // fence write->read order

                // prefetch row r+1 (hides under compute below)
                if (r + 1 < in_rows) {
                    const size_t base = (size_t)(r0 + r + 1) * 512 + col;
                    rf = Fp[base]; rg = Ip[base]; rv = Vp[base];
                    if (halo_ok) {
                        const size_t bh = (size_t)(r0 + r + 1) * 512 + colH;
                        rf2 = Fp[bh]; rg2 = Ip[bh]; rv2 = Vp[bh];
                    }
                }

                // horizontal gaussian sums, packed-f32; capture k=1 tap
                f32x2 hfhi  = (f32x2)(0.f);
                f32x2 hffii = (f32x2)(0.f);
                f32x2 hfifv = (f32x2)(0.f);
                f32x2 hvvv  = (f32x2)(0.f);
                f32x2 fi1 = (f32x2)(0.f); float v1 = 0.f;
#pragma unroll
                for (int k = 0; k < 11; ++k) {
                    const float t = w6[k < 6 ? k : 10 - k];
                    const f32x2 fi = srow_fi[wv][lane + k];
                    const float V  = srow_v [wv][lane + k];
                    if (k == 1) { fi1 = fi; v1 = V; }
                    const f32x2 t2 = (f32x2){t, t};
                    const f32x2 tfi = t2 * fi;                      // pk_mul
                    hfhi  = __builtin_elementwise_fma(t2,  fi, hfhi);   // pk_fma
                    hffii = __builtin_elementwise_fma(tfi, fi, hffii);  // pk_fma
                    hfifv.x = fmaf(tfi.x, fi.y, hfifv.x);
                    hfifv.y = fmaf(tfi.x, V,    hfifv.y);
                    const float tV = t * V;
                    hvvv.x = fmaf(t,  V, hvvv.x);
                    hvvv.y = fmaf(tV, V, hvvv.y);
                }

                // lapl column sums: left from LDS, right = gaussian k=1 tap
                const bool lap_row = (r <= 43) || last;
                f32x2 csFI_cur = (f32x2)(0.f); float csV_cur = 0.f;
                if (lap_row) {
                    const f32x2 fiL = srow_fi[wv][il];
                    const float vL  = srow_v [wv][il];
                    f32x2 fiR = fi1; float vR = v1;
                    if (rt_edge) { fiR = fiL; vR = vL; }   // col 511 reflect
                    csFI_cur = fiL + fiR + (f32x2){curF, curI};
                    csV_cur  = vL  + vR  + curV;
                }
                __builtin_amdgcn_wave_barrier();  // fence read->next-write

                // vertical ring: k=0 OVERWRITES slot p, k>=1 accumulates.
                {
                    const f32x2 w02 = (f32x2){w6[0], w6[0]};
                    acc[p][0] = w02 * hfhi;
                    acc[p][1] = w02 * hffii;
                    acc[p][2] = w02 * hfifv;
                    acc[p][3] = w02 * hvvv;
                }
#pragma unroll
                for (int k = 1; k < 11; ++k) {
                    const int s = (p - k + 11) % 11;   // compile-time
                    const float t = w6[k < 6 ? k : 10 - k];
                    const f32x2 t2 = (f32x2){t, t};
                    acc[s][0] = __builtin_elementwise_fma(t2, hfhi,  acc[s][0]);
                    acc[s][1] = __builtin_elementwise_fma(t2, hffii, acc[s][1]);
                    acc[s][2] = __builtin_elementwise_fma(t2, hfifv, acc[s][2]);
                    acc[s][3] = __builtin_elementwise_fma(t2, hvvv,  acc[s][3]);
                }
                // ssim finalize output row r-10
                if (r >= 10) {
                    const int s = (p + 1) % 11;        // compile-time
                    const float mu1 = acc[s][0].x, mu2 = acc[s][0].y, mu3 = acc[s][3].x;
                    const float eff = acc[s][1].x, eii = acc[s][1].y, evv = acc[s][3].y;
                    const float efi = acc[s][2].x, efv = acc[s][2].y;
                    const float mu1sq = mu1*mu1, mu2sq = mu2*mu2, mu3sq = mu3*mu3;
                    const float mu12 = mu1*mu2, mu13 = mu1*mu3;
                    const float sf  = eff - mu1sq;
                    const float si  = eii - mu2sq;
                    const float sv  = evv - mu3sq;
                    const float s12 = efi - mu12;
                    const float s13 = efv - mu13;
                    const float n1 = (2.f*mu12 + SSIM_C1) * (2.f*s12 + SSIM_C2);
                    const float d1 = (mu1sq + mu2sq + SSIM_C1) * (sf + si + SSIM_C2);
                    const float n2 = (2.f*mu13 + SSIM_C1) * (2.f*s13 + SSIM_C2);
                    const float d2 = (mu1sq + mu3sq + SSIM_C1) * (sf + sv + SSIM_C2);
                    const float q1 = __builtin_amdgcn_rcpf(d1);   // ~2^-22 vs 6.6e-2 tol
                    const float q2 = __builtin_amdgcn_rcpf(d2);
                    if (col_ok) lssim += fmaf(n1, q1, n2 * q2);
                }
                // laplacian + l1 for row y = r0 + r - 1 (16x-unscaled lapl)
                if (r >= 2 && lap_row) {
                    const f32x2 sFI = csFI_2 + csFI_1 + csFI_cur;
                    const float sV  = csV_2 + csV_1 + csV_cur;
                    const f32x2 lFI = __builtin_elementwise_fma(
                                         (f32x2){-9.f,-9.f}, cPrevFI, sFI);
                    const float lV  = fmaf(-9.f, cPrevV, sV);
                    grs += fabsf(fmaxf(fabsf(lFI.y), fabsf(lV)) - fabsf(lFI.x));
                    l1s += fabsf(fmaxf(m1r, m2r) - cPrevFI.x);
                }
                if (first && r == 1) {  // y = 0: reflect row -1 -> row 1
                    const f32x2 sFI = csFI_1 + csFI_cur + csFI_cur;
                    const float sV  = csV_1 + csV_cur + csV_cur;
                    const f32x2 lFI = __builtin_elementwise_fma(
                                         (f32x2){-9.f,-9.f}, cPrevFI, sFI);
                    const float lV  = fmaf(-9.f, cPrevV, sV);
                    grs += fabsf(fmaxf(fabsf(lFI.y), fabsf(lV)) - fabsf(lFI.x));
                    l1s += fabsf(fmaxf(m1r, m2r) - cPrevFI.x);
                }
                // shift history; prefetch mir/mvi row r0+r (used next step)
                if (lap_row) {
                    csFI_2 = csFI_1; csFI_1 = csFI_cur;
                    csV_2  = csV_1;  csV_1  = csV_cur;
                    cPrevFI = (f32x2){curF, curI}; cPrevV = curV;
                    const int ny = min(r0 + r, 511);
                    const size_t bm = (size_t)ny * 512 + col;
                    m1r = mir[bm]; m2r = mvi[bm];
                }
            }
        }
    }

    // epilogue: last strip handles row 511 (reflect row 512 -> 510)
    if (last) {
        const size_t bm = (size_t)511 * 512 + col;
        const float m1e = mir[bm], m2e = mvi[bm];
        const f32x2 sFI = csFI_2 + csFI_2 + csFI_1;
        const float sV  = csV_2 + csV_2 + csV_1;
        const f32x2 lFI = __builtin_elementwise_fma((f32x2){-9.f,-9.f}, cPrevFI, sFI);
        const float lV  = fmaf(-9.f, cPrevV, sV);
        grs += fabsf(fmaxf(fabsf(lFI.y), fabsf(lV)) - fabsf(lFI.x));
        l1s += fabsf(fmaxf(m1e, m2e) - cPrevFI.x);
    }

    // cross-wave block reduction -> three partial writes (no atomics)
#pragma unroll
    for (int off = 32; off > 0; off >>= 1) {
        lssim += __shfl_down(lssim, off);
        l1s   += __shfl_down(l1s, off);
        grs   += __shfl_down(grs, off);
    }
    __shared__ float red[12];
    if (lane == 0) { red[wv] = lssim; red[4 + wv] = l1s; red[8 + wv] = grs; }
    __syncthreads();
    if (tid == 0) {
        const int blk = blockIdx.x + 2 * (blockIdx.y + 12 * blockIdx.z); // 0..767
        ws[blk]        = red[0] + red[1] + red[2] + red[3];
        ws[768 + blk]  = red[4] + red[5] + red[6] + red[7];
        ws[1536 + blk] = (red[8] + red[9] + red[10] + red[11]) * 0.0625f; // /16
    }
}

// ---------------- final combine: reduce all partials ------------------------
__global__ void final_kernel(const float* __restrict__ ws, float* __restrict__ out)
{
    const int tid = threadIdx.x;
    float s0 = 0.f, s1 = 0.f, s2 = 0.f;
#pragma unroll
    for (int i = tid; i < 768; i += 256) {
        s0 += ws[i];
        s1 += ws[768 + i];
        s2 += ws[1536 + i];
    }
#pragma unroll
    for (int off = 32; off > 0; off >>= 1) {
        s0 += __shfl_down(s0, off);
        s1 += __shfl_down(s1, off);
        s2 += __shfl_down(s2, off);
    }
    __shared__ float red[12];
    if ((tid & 63) == 0) {
        red[tid >> 6] = s0; red[4 + (tid >> 6)] = s1; red[8 + (tid >> 6)] = s2;
    }
    __syncthreads();
    if (tid == 0) {
        const float ssim_sum = red[0] + red[1] + red[2] + red[3];
        const float l1_sum   = red[4] + red[5] + red[6] + red[7];
        const float gr_sum   = red[8] + red[9] + red[10] + red[11];
        const float ms = 2.f - ssim_sum / 8064128.f;   // 32*502*502
        const float l1 = l1_sum / 8388608.f;           // 32*512*512
        const float gr = gr_sum / 8388608.f;
        out[0] = ms + l1 + 10.f * gr;
    }
}

extern "C" void kernel_launch(void* const* d_in, const int* in_sizes, int n_in,
                              void* d_out, int out_size, void* d_ws, size_t ws_size,
                              hipStream_t stream)
{
    const float* fus = (const float*)d_in[0];
    const float* irp = (const float*)d_in[1];
    const float* vip = (const float*)d_in[2];
    const float* mir = (const float*)d_in[3];
    const float* mvi = (const float*)d_in[4];
    float* out = (float*)d_out;
    float* ws  = (float*)d_ws;

    // gaussian window (matches np: f64 normalize, cast to f32)
    GaussW gw;
    double g[11], s = 0.0;
    for (int i = 0; i < 11; ++i) {
        const double d = (double)i - 5.0;
        g[i] = std::exp(-(d * d) / (2.0 * 1.5 * 1.5));
        s += g[i];
    }
    for (int i = 0; i < 11; ++i) gw.w[i] = (float)(g[i] / s);

    ssim_kernel<<<dim3(2, 12, 32), 256, 0, stream>>>(fus, irp, vip, mir, mvi,
                                                     ws, gw);
    final_kernel<<<1, 256, 0, stream>>>(ws, out);
}

// Round 16
// 90.033 us; speedup vs baseline: 1.3392x; 1.0715x over previous
//
#include <hip/hip_runtime.h>
#include <cmath>

// FusionLoss = ms_ssim(fus,ir)+ms_ssim(fus,vi) + l1(max(map_ir,map_vi),fus)
//            + 10*mean(|max(|lap ir|,|lap vi|) - |lap fus||)
// Inputs: im_fus, im_ir, im_vi, map_ir, map_vi  each [32,1,512,512] fp32.
//
// d_ws layout (floats): [0..768) ssim | [768..1536) l1 | [1536..2304) grad
//
// Journal: r2 atomics->partials. r9/r12 pk-f32 ssim 72.9us @ VGPR 84.
// r14 lapl rides ssim pipeline (103.8). r15 DS-diet + reg-diet: 96.5us,
// VGPR 92, VALUBusy 43%, HBM 10%. Pipe floors: DS ~43us, VALU ~23us,
// HBM ~27us -> at ~93us the kernel is DS-LATENCY bound (serial
// write->read->fma chain per row, 3 waves/SIMD can't hide ~120cyc).
// r16: PAIR-ROW processing — stage rows r,r+1 into two LDS row buffers,
// issue all 44 tap reads as one stream (one exposed-latency window per
// PAIR), two independent h-sum chains for VALU ILP. in_rows always even
// (52/50) so pairs never split; ring slots (2p+c)%11 compile-time.
// Centers/right-taps come free from k=0/k=1 taps.
// GUARDS: WRITE<=50KB, VGPR<=128 else spill -> revert to r15.

typedef float f32x2 __attribute__((ext_vector_type(2)));

struct GaussW { float w[11]; };

#define SSIM_C1 1.0e-4f
#define SSIM_C2 9.0e-4f

// ---------------- fused SSIM + L1 + laplacian kernel ------------------------
// Grid: (2 col blocks of 256, 12 row strips of 42, 32 batch) = 768 blocks
// = 3 blocks/CU resident. Block = 4 independent waves; wave wv owns 64 cols;
// wave-private LDS rows; no __syncthreads in the main loop (in-order DS pipe
// within a wave; wave_barrier() fences compiler reordering).
// Laplacian row coverage: strip rs owns y in [42rs+1, 42rs+42]; strip 0
// adds y=0 (reflect); strip 11 covers [463,510] + epilogue 511.
__global__ __launch_bounds__(256, 2)
void ssim_kernel(const float* __restrict__ fus, const float* __restrict__ irp,
                 const float* __restrict__ vip, const float* __restrict__ mir,
                 const float* __restrict__ mvi, float* __restrict__ ws,
                 GaussW gw)
{
    const int b    = blockIdx.z;
    const int rs   = blockIdx.y;
    const int r0   = rs * 42;
    const int tid  = threadIdx.x;
    const int wv   = tid >> 6;          // wave 0..3
    const int lane = tid & 63;
    const int c0   = blockIdx.x * 256 + wv * 64;   // wave's column base
    const int out_rows = min(42, 502 - r0);        // last strip: 40
    const int in_rows  = out_rows + 10;            // 52 or 50 (always even)
    const bool first = (rs == 0);
    const bool last  = (rs == 11);

    const size_t ib = (size_t)b * 512 * 512;
    const float* __restrict__ Fp = fus + ib;
    const float* __restrict__ Ip = irp + ib;
    const float* __restrict__ Vp = vip + ib;
    mir += ib;
    mvi += ib;

    __shared__ f32x2 srow_fi[4][2][80]; // [wave][row-of-pair][col]; 64 main + 10 right halo + [74] left halo
    __shared__ float srow_v [4][2][80];

    float w6[6];                        // gaussian symmetric: w[k]=w[10-k]
#pragma unroll
    for (int k = 0; k < 6; ++k) w6[k] = gw.w[k];

    f32x2 acc[11][4];                   // ring: [0]={hf,hi} [1]={hff,hii} [2]={hfi,hfv} [3]={hv,hvv}
#pragma unroll
    for (int s = 0; s < 11; ++s)
#pragma unroll
        for (int q = 0; q < 4; ++q) acc[s][q] = (f32x2)(0.f);

    float lssim = 0.f, l1s = 0.f, grs = 0.f;
    const int  col      = c0 + lane;
    const bool col_ok   = col <= 501;             // ssim-valid output column
    // unified halo loader: lanes 0..9 -> right halo, lane 10 -> left halo (idx 74)
    const bool is_left  = (lane == 10);
    const int  colH     = is_left ? (c0 - 1) : (c0 + 64 + lane);
    const bool halo_ok  = (lane < 10) ? (colH < 512) : (is_left && c0 > 0);
    const int  hidx     = 64 + lane;              // lane10 -> 74
    // lapl neighbor LDS index (reflect at image edges)
    const int il       = (lane == 0) ? ((c0 == 0) ? 1 : 74) : (lane - 1);
    const bool rt_edge = (lane == 63) && (c0 + 64 >= 512);  // col 511: right=reflect=left

    // laplacian history (column sums of the 2 previous rows; center of prev row)
    f32x2 csFI_1 = (f32x2)(0.f), csFI_2 = (f32x2)(0.f);
    float csV_1 = 0.f, csV_2 = 0.f;
    f32x2 cPrevFI = (f32x2)(0.f); float cPrevV = 0.f;
    // mir/mvi prefetch: mA = row r0+r-1 (for y1), mB = row r0+r (for y2)
    float mA1 = 0.f, mA2 = 0.f, mB1, mB2;

    // prologue: prefetch rows 0 (A) and 1 (B), main + unified halo; mB = row r0
    float arf, arg, arv, arf2 = 0.f, arg2 = 0.f, arv2 = 0.f;
    float brf, brg, brv, brf2 = 0.f, brg2 = 0.f, brv2 = 0.f;
    {
        const size_t b0 = (size_t)r0 * 512 + col;
        arf = Fp[b0]; arg = Ip[b0]; arv = Vp[b0];
        const size_t b1 = (size_t)(r0 + 1) * 512 + col;
        brf = Fp[b1]; brg = Ip[b1]; brv = Vp[b1];
        if (halo_ok) {
            const size_t h0 = (size_t)r0 * 512 + colH;
            arf2 = Fp[h0]; arg2 = Ip[h0]; arv2 = Vp[h0];
            const size_t h1 = (size_t)(r0 + 1) * 512 + colH;
            brf2 = Fp[h1]; brg2 = Ip[h1]; brv2 = Vp[h1];
        }
        mB1 = mir[b0]; mB2 = mvi[b0];
    }

#pragma unroll 1
    for (int rb = 0; rb < 66; rb += 22) {
#pragma unroll
        for (int p = 0; p < 11; ++p) {
            const int r = rb + 2 * p;             // even row of the pair
            if (r < in_rows) {                    // wave-uniform; covers r+1 too
                // stage both rows (b64 pair + b32 V each, + unified halo)
                srow_fi[wv][0][lane] = (f32x2){arf, arg};
                srow_v [wv][0][lane] = arv;
                srow_fi[wv][1][lane] = (f32x2){brf, brg};
                srow_v [wv][1][lane] = brv;
                if (halo_ok) {
                    srow_fi[wv][0][hidx] = (f32x2){arf2, arg2};
                    srow_v [wv][0][hidx] = arv2;
                    srow_fi[wv][1][hidx] = (f32x2){brf2, brg2};
                    srow_v [wv][1][hidx] = brv2;
                }
                __builtin_amdgcn_wave_barrier();  // fence write->read order

                // prefetch rows r+2 (A) and r+3 (B); consumed next pair
                if (r + 2 < in_rows) {
                    const size_t bA = (size_t)(r0 + r + 2) * 512 + col;
                    arf = Fp[bA]; arg = Ip[bA]; arv = Vp[bA];
                    const size_t bB = (size_t)(r0 + r + 3) * 512 + col;
                    brf = Fp[bB]; brg = Ip[bB]; brv = Vp[bB];
                    if (halo_ok) {
                        const size_t hA = (size_t)(r0 + r + 2) * 512 + colH;
                        arf2 = Fp[hA]; arg2 = Ip[hA]; arv2 = Vp[hA];
                        const size_t hB = (size_t)(r0 + r + 3) * 512 + colH;
                        brf2 = Fp[hB]; brg2 = Ip[hB]; brv2 = Vp[hB];
                    }
                }

                // horizontal gaussian sums for BOTH rows (one read stream,
                // two independent dependency chains); capture k=0 (center)
                // and k=1 (right neighbor) taps for the laplacian.
                f32x2 hfhiA = (f32x2)(0.f), hffiiA = (f32x2)(0.f);
                f32x2 hfifvA = (f32x2)(0.f), hvvvA = (f32x2)(0.f);
                f32x2 hfhiB = (f32x2)(0.f), hffiiB = (f32x2)(0.f);
                f32x2 hfifvB = (f32x2)(0.f), hvvvB = (f32x2)(0.f);
                f32x2 fi0A = (f32x2)(0.f), fi1A = (f32x2)(0.f);
                f32x2 fi0B = (f32x2)(0.f), fi1B = (f32x2)(0.f);
                float v0A = 0.f, v1A = 0.f, v0B = 0.f, v1B = 0.f;
#pragma unroll
                for (int k = 0; k < 11; ++k) {
                    const float t = w6[k < 6 ? k : 10 - k];
                    const f32x2 t2 = (f32x2){t, t};
                    const f32x2 fiA = srow_fi[wv][0][lane + k];
                    const float VA  = srow_v [wv][0][lane + k];
                    const f32x2 fiB = srow_fi[wv][1][lane + k];
                    const float VB  = srow_v [wv][1][lane + k];
                    if (k == 0) { fi0A = fiA; v0A = VA; fi0B = fiB; v0B = VB; }
                    if (k == 1) { fi1A = fiA; v1A = VA; fi1B = fiB; v1B = VB; }
                    const f32x2 tfiA = t2 * fiA;
                    hfhiA  = __builtin_elementwise_fma(t2,   fiA, hfhiA);
                    hffiiA = __builtin_elementwise_fma(tfiA, fiA, hffiiA);
                    hfifvA.x = fmaf(tfiA.x, fiA.y, hfifvA.x);
                    hfifvA.y = fmaf(tfiA.x, VA,    hfifvA.y);
                    hvvvA.x = fmaf(t,      VA, hvvvA.x);
                    hvvvA.y = fmaf(t * VA, VA, hvvvA.y);
                    const f32x2 tfiB = t2 * fiB;
                    hfhiB  = __builtin_elementwise_fma(t2,   fiB, hfhiB);
                    hffiiB = __builtin_elementwise_fma(tfiB, fiB, hffiiB);
                    hfifvB.x = fmaf(tfiB.x, fiB.y, hfifvB.x);
                    hfifvB.y = fmaf(tfiB.x, VB,    hfifvB.y);
                    hvvvB.x = fmaf(t,      VB, hvvvB.x);
                    hvvvB.y = fmaf(t * VB, VB, hvvvB.y);
                }

                // lapl column sums for both rows (left from LDS, right = k=1 tap)
                const bool lap = (r <= 43) || last;
                f32x2 csA_FI = (f32x2)(0.f), csB_FI = (f32x2)(0.f);
                float csA_V = 0.f, csB_V = 0.f;
                if (lap) {
                    const f32x2 fiLA = srow_fi[wv][0][il];
                    const float vLA  = srow_v [wv][0][il];
                    const f32x2 fiLB = srow_fi[wv][1][il];
                    const float vLB  = srow_v [wv][1][il];
                    f32x2 fiRA = fi1A; float vRA = v1A;
                    f32x2 fiRB = fi1B; float vRB = v1B;
                    if (rt_edge) { fiRA = fiLA; vRA = vLA; fiRB = fiLB; vRB = vLB; }
                    csA_FI = fiLA + fiRA + fi0A;  csA_V = vLA + vRA + v0A;
                    csB_FI = fiLB + fiRB + fi0B;  csB_V = vLB + vRB + v0B;
                }
                __builtin_amdgcn_wave_barrier();  // fence read->next-write

                // ---- row r: ring update then finalize output r-10 ----
                {
                    const f32x2 w02 = (f32x2){w6[0], w6[0]};
                    acc[(2*p) % 11][0] = w02 * hfhiA;
                    acc[(2*p) % 11][1] = w02 * hffiiA;
                    acc[(2*p) % 11][2] = w02 * hfifvA;
                    acc[(2*p) % 11][3] = w02 * hvvvA;
                }
#pragma unroll
                for (int k = 1; k < 11; ++k) {
                    const int s = (2*p - k + 22) % 11;   // compile-time
                    const float t = w6[k < 6 ? k : 10 - k];
                    const f32x2 t2 = (f32x2){t, t};
                    acc[s][0] = __builtin_elementwise_fma(t2, hfhiA,  acc[s][0]);
                    acc[s][1] = __builtin_elementwise_fma(t2, hffiiA, acc[s][1]);
                    acc[s][2] = __builtin_elementwise_fma(t2, hfifvA, acc[s][2]);
                    acc[s][3] = __builtin_elementwise_fma(t2, hvvvA,  acc[s][3]);
                }
                if (r >= 10) {
                    const int s = (2*p + 1) % 11;        // compile-time
                    const float mu1 = acc[s][0].x, mu2 = acc[s][0].y, mu3 = acc[s][3].x;
                    const float eff = acc[s][1].x, eii = acc[s][1].y, evv = acc[s][3].y;
                    const float efi = acc[s][2].x, efv = acc[s][2].y;
                    const float mu1sq = mu1*mu1, mu2sq = mu2*mu2, mu3sq = mu3*mu3;
                    const float mu12 = mu1*mu2, mu13 = mu1*mu3;
                    const float sf  = eff - mu1sq;
                    const float si  = eii - mu2sq;
                    const float sv  = evv - mu3sq;
                    const float s12 = efi - mu12;
                    const float s13 = efv - mu13;
                    const float n1 = (2.f*mu12 + SSIM_C1) * (2.f*s12 + SSIM_C2);
                    const float d1 = (mu1sq + mu2sq + SSIM_C1) * (sf + si + SSIM_C2);
                    const float n2 = (2.f*mu13 + SSIM_C1) * (2.f*s13 + SSIM_C2);
                    const float d2 = (mu1sq + mu3sq + SSIM_C1) * (sf + sv + SSIM_C2);
                    const float q1 = __builtin_amdgcn_rcpf(d1);   // ~2^-22 vs 6.6e-2 tol
                    const float q2 = __builtin_amdgcn_rcpf(d2);
                    if (col_ok) lssim += fmaf(n1, q1, n2 * q2);
                }
                // ---- row r+1: ring update then finalize output r-9 ----
                {
                    const f32x2 w02 = (f32x2){w6[0], w6[0]};
                    acc[(2*p + 1) % 11][0] = w02 * hfhiB;
                    acc[(2*p + 1) % 11][1] = w02 * hffiiB;
                    acc[(2*p + 1) % 11][2] = w02 * hfifvB;
                    acc[(2*p + 1) % 11][3] = w02 * hvvvB;
                }
#pragma unroll
                for (int k = 1; k < 11; ++k) {
                    const int s = (2*p + 1 - k + 22) % 11;   // compile-time
                    const float t = w6[k < 6 ? k : 10 - k];
                    const f32x2 t2 = (f32x2){t, t};
                    acc[s][0] = __builtin_elementwise_fma(t2, hfhiB,  acc[s][0]);
                    acc[s][1] = __builtin_elementwise_fma(t2, hffiiB, acc[s][1]);
                    acc[s][2] = __builtin_elementwise_fma(t2, hfifvB, acc[s][2]);
                    acc[s][3] = __builtin_elementwise_fma(t2, hvvvB,  acc[s][3]);
                }
                if (r >= 10) {
                    const int s = (2*p + 2) % 11;        // compile-time
                    const float mu1 = acc[s][0].x, mu2 = acc[s][0].y, mu3 = acc[s][3].x;
                    const float eff = acc[s][1].x, eii = acc[s][1].y, evv = acc[s][3].y;
                    const float efi = acc[s][2].x, efv = acc[s][2].y;
                    const float mu1sq = mu1*mu1, mu2sq = mu2*mu2, mu3sq = mu3*mu3;
                    const float mu12 = mu1*mu2, mu13 = mu1*mu3;
                    const float sf  = eff - mu1sq;
                    const float si  = eii - mu2sq;
                    const float sv  = evv - mu3sq;
                    const float s12 = efi - mu12;
                    const float s13 = efv - mu13;
                    const float n1 = (2.f*mu12 + SSIM_C1) * (2.f*s12 + SSIM_C2);
                    const float d1 = (mu1sq + mu2sq + SSIM_C1) * (sf + si + SSIM_C2);
                    const float n2 = (2.f*mu13 + SSIM_C1) * (2.f*s13 + SSIM_C2);
                    const float d2 = (mu1sq + mu3sq + SSIM_C1) * (sf + sv + SSIM_C2);
                    const float q1 = __builtin_amdgcn_rcpf(d1);
                    const float q2 = __builtin_amdgcn_rcpf(d2);
                    if (col_ok) lssim += fmaf(n1, q1, n2 * q2);
                }

                // ---- laplacian + l1 emissions (16x-unscaled lapl) ----
                if (lap) {
                    if (r >= 2) {
                        // y1 = r0+r-1: rows r-2, r-1, r; center row r-1
                        const f32x2 sFI = csFI_2 + csFI_1 + csA_FI;
                        const float sV  = csV_2 + csV_1 + csA_V;
                        const f32x2 lFI = __builtin_elementwise_fma(
                                             (f32x2){-9.f,-9.f}, cPrevFI, sFI);
                        const float lV  = fmaf(-9.f, cPrevV, sV);
                        grs += fabsf(fmaxf(fabsf(lFI.y), fabsf(lV)) - fabsf(lFI.x));
                        l1s += fabsf(fmaxf(mA1, mA2) - cPrevFI.x);
                        // y2 = r0+r: rows r-1, r, r+1; center row r
                        const f32x2 sFI2 = csFI_1 + csA_FI + csB_FI;
                        const float sV2  = csV_1 + csA_V + csB_V;
                        const f32x2 lFI2 = __builtin_elementwise_fma(
                                             (f32x2){-9.f,-9.f}, fi0A, sFI2);
                        const float lV2  = fmaf(-9.f, v0A, sV2);
                        grs += fabsf(fmaxf(fabsf(lFI2.y), fabsf(lV2)) - fabsf(lFI2.x));
                        l1s += fabsf(fmaxf(mB1, mB2) - fi0A.x);
                    }
                    if (first && r == 0) {
                        // y = 0: rows reflect(-1)=1, 0, 1; center row 0
                        const f32x2 sFI = csA_FI + csB_FI + csB_FI;
                        const float sV  = csA_V + csB_V + csB_V;
                        const f32x2 lFI = __builtin_elementwise_fma(
                                             (f32x2){-9.f,-9.f}, fi0A, sFI);
                        const float lV  = fmaf(-9.f, v0A, sV);
                        grs += fabsf(fmaxf(fabsf(lFI.y), fabsf(lV)) - fabsf(lFI.x));
                        l1s += fabsf(fmaxf(mB1, mB2) - fi0A.x);
                    }
                    // shift history by 2 rows; prefetch m rows for next pair
                    csFI_2 = csA_FI; csFI_1 = csB_FI;
                    csV_2  = csA_V;  csV_1  = csB_V;
                    cPrevFI = fi0B;  cPrevV = v0B;
                    if (r + 2 < in_rows) {
                        const int yA = min(r0 + r + 1, 511);
                        const int yB = min(r0 + r + 2, 511);
                        const size_t bmA = (size_t)yA * 512 + col;
                        const size_t bmB = (size_t)yB * 512 + col;
                        mA1 = mir[bmA]; mA2 = mvi[bmA];
                        mB1 = mir[bmB]; mB2 = mvi[bmB];
                    }
                }
            }
        }
    }

    // epilogue: last strip handles row 511 (reflect row 512 -> 510)
    if (last) {
        const size_t bm = (size_t)511 * 512 + col;
        const float m1e = mir[bm], m2e = mvi[bm];
        const f32x2 sFI = csFI_2 + csFI_2 + csFI_1;
        const float sV  = csV_2 + csV_2 + csV_1;
        const f32x2 lFI = __builtin_elementwise_fma((f32x2){-9.f,-9.f}, cPrevFI, sFI);
        const float lV  = fmaf(-9.f, cPrevV, sV);
        grs += fabsf(fmaxf(fabsf(lFI.y), fabsf(lV)) - fabsf(lFI.x));
        l1s += fabsf(fmaxf(m1e, m2e) - cPrevFI.x);
    }

    // cross-wave block reduction -> three partial writes (no atomics)
#pragma unroll
    for (int off = 32; off > 0; off >>= 1) {
        lssim += __shfl_down(lssim, off);
        l1s   += __shfl_down(l1s, off);
        grs   += __shfl_down(grs, off);
    }
    __shared__ float red[12];
    if (lane == 0) { red[wv] = lssim; red[4 + wv] = l1s; red[8 + wv] = grs; }
    __syncthreads();
    if (tid == 0) {
        const int blk = blockIdx.x + 2 * (blockIdx.y + 12 * blockIdx.z); // 0..767
        ws[blk]        = red[0] + red[1] + red[2] + red[3];
        ws[768 + blk]  = red[4] + red[5] + red[6] + red[7];
        ws[1536 + blk] = (red[8] + red[9] + red[10] + red[11]) * 0.0625f; // /16
    }
}

// ---------------- final combine: reduce all partials ------------------------
__global__ void final_kernel(const float* __restrict__ ws, float* __restrict__ out)
{
    const int tid = threadIdx.x;
    float s0 = 0.f, s1 = 0.f, s2 = 0.f;
#pragma unroll
    for (int i = tid; i < 768; i += 256) {
        s0 += ws[i];
        s1 += ws[768 + i];
        s2 += ws[1536 + i];
    }
#pragma unroll
    for (int off = 32; off > 0; off >>= 1) {
        s0 += __shfl_down(s0, off);
        s1 += __shfl_down(s1, off);
        s2 += __shfl_down(s2, off);
    }
    __shared__ float red[12];
    if ((tid & 63) == 0) {
        red[tid >> 6] = s0; red[4 + (tid >> 6)] = s1; red[8 + (tid >> 6)] = s2;
    }
    __syncthreads();
    if (tid == 0) {
        const float ssim_sum = red[0] + red[1] + red[2] + red[3];
        const float l1_sum   = red[4] + red[5] + red[6] + red[7];
        const float gr_sum   = red[8] + red[9] + red[10] + red[11];
        const float ms = 2.f - ssim_sum / 8064128.f;   // 32*502*502
        const float l1 = l1_sum / 8388608.f;           // 32*512*512
        const float gr = gr_sum / 8388608.f;
        out[0] = ms + l1 + 10.f * gr;
    }
}

extern "C" void kernel_launch(void* const* d_in, const int* in_sizes, int n_in,
                              void* d_out, int out_size, void* d_ws, size_t ws_size,
                              hipStream_t stream)
{
    const float* fus = (const float*)d_in[0];
    const float* irp = (const float*)d_in[1];
    const float* vip = (const float*)d_in[2];
    const float* mir = (const float*)d_in[3];
    const float* mvi = (const float*)d_in[4];
    float* out = (float*)d_out;
    float* ws  = (float*)d_ws;

    // gaussian window (matches np: f64 normalize, cast to f32)
    GaussW gw;
    double g[11], s = 0.0;
    for (int i = 0; i < 11; ++i) {
        const double d = (double)i - 5.0;
        g[i] = std::exp(-(d * d) / (2.0 * 1.5 * 1.5));
        s += g[i];
    }
    for (int i = 0; i < 11; ++i) gw.w[i] = (float)(g[i] / s);

    ssim_kernel<<<dim3(2, 12, 32), 256, 0, stream>>>(fus, irp, vip, mir, mvi,
                                                     ws, gw);
    final_kernel<<<1, 256, 0, stream>>>(ws, out);
}